// Round 15
// baseline (3720.691 us; speedup 1.0000x reference)
//
#include <hip/hip_runtime.h>
#include <cstdint>
#include <cstddef>

// GRU-D: B=64, T=512, D=256, H=1024.
// v14 = v13 scan (proven, 3.04 ms) + MFMA projection:
//  - proj_mfma_k: 64x64 tiles, x staged f32->f16 in LDS, W^T f16 B-operand,
//    same MFMA fragment pattern as the proven scan kernel.
//  - pack_x_k / pack_rows_k / x2 / W2 removed; W transposed by the generic
//    transpose kernel (also used for U).
// scan_k byte-identical to v13.

#define NB 64
#define NT 512
#define ND 256
#define NH 1024

typedef _Float16 h2_t __attribute__((ext_vector_type(2)));
typedef _Float16 half8 __attribute__((ext_vector_type(8)));
typedef float f32x4 __attribute__((ext_vector_type(4)));
typedef uint32_t u32x4 __attribute__((ext_vector_type(4)));

__device__ __forceinline__ uint32_t pack2(float a, float b) {
  h2_t v; v[0] = (_Float16)a; v[1] = (_Float16)b;
  return __builtin_bit_cast(uint32_t, v);
}
__device__ __forceinline__ uint16_t f2h(float x) {
  _Float16 v = (_Float16)x; return __builtin_bit_cast(uint16_t, v);
}
__device__ __forceinline__ float h2f(uint16_t u) {
  return (float)__builtin_bit_cast(_Float16, u);
}
__device__ __forceinline__ float sigm(float x) {
  return 1.f / (1.f + __expf(-x));
}
__device__ __forceinline__ float fast_tanh(float x) {
  float e = __expf(2.f * x);
  return 1.f - 2.f / (e + 1.f);
}
__device__ __forceinline__ float ldnt_h(const uint16_t* p) {
  return h2f(__builtin_nontemporal_load(p));
}
__device__ __forceinline__ void stnt_f(float* p, float v) {
  __builtin_nontemporal_store(v, p);
}

// device-coherent (bypass L1/L2, served at MALL)
__device__ __forceinline__ u32x4 ld_cg_b128(const uint32_t* p) {
  u32x4 v;
  asm volatile("global_load_dwordx4 %0, %1, off sc0 sc1" : "=v"(v) : "v"(p) : "memory");
  return v;
}
__device__ __forceinline__ void st_cg_b128(uint32_t* p, u32x4 v) {
  asm volatile("global_store_dwordx4 %0, %1, off sc0 sc1" :: "v"(p), "v"(v) : "memory");
}
__device__ __forceinline__ void st_cg_b32(uint32_t* p, unsigned v) {
  asm volatile("global_store_dword %0, %1, off sc0 sc1" :: "v"(p), "v"(v) : "memory");
}
__device__ __forceinline__ unsigned ld_cg_b32w(const uint32_t* p) {
  unsigned v;
  asm volatile("global_load_dword %0, %1, off sc0 sc1\n\ts_waitcnt vmcnt(0)"
               : "=v"(v) : "v"(p) : "memory");
  return v;
}

// ---- generic transpose: src [R][C] f32 -> dst [C][R] f16, 64x64 tiles ---
__global__ __launch_bounds__(256) void transpose_f2h_g(
    const float* __restrict__ src, uint16_t* __restrict__ dst, int R, int C) {
  __shared__ uint16_t lt[64][68];
  int tpc = C >> 6;                       // tiles along C
  int tr = blockIdx.x / tpc, tc = blockIdx.x % tpc;
  int tid = threadIdx.x;
  int r0 = tid >> 6, cc = tid & 63;
#pragma unroll
  for (int it = 0; it < 16; ++it) {
    int r = it * 4 + r0;
    lt[cc][r] = f2h(src[(size_t)(tr * 64 + r) * C + tc * 64 + cc]);
  }
  __syncthreads();
#pragma unroll
  for (int it = 0; it < 16; ++it) {
    int c = it * 4 + r0;
    dst[(size_t)(tc * 64 + c) * R + tr * 64 + cc] = lt[c][cc];
  }
}

// ---- MFMA input projection ---------------------------------------------
// out[n][gc] = x[n,:] @ W[:,gc] + bias; gate a = cg>>4; gamma = exp(-relu).
// Tile 64 rows x 64 cols; grid 512*64. Fragment pattern copied from scan_k.
__global__ __launch_bounds__(256) void proj_mfma_k(
    const float* __restrict__ x, const uint16_t* __restrict__ WT,
    const float* __restrict__ bd, const float* __restrict__ bz,
    const float* __restrict__ br, const float* __restrict__ bh,
    uint16_t* __restrict__ g_gamma, uint16_t* __restrict__ g_xz,
    uint16_t* __restrict__ g_xr, uint16_t* __restrict__ g_xh) {
  __shared__ __align__(16) uint16_t As[64][264];
  const int tid = threadIdx.x;
  const int rg = blockIdx.x >> 6;
  const int cg = blockIdx.x & 63;
  const int lane = tid & 63, w = tid >> 6;
  const int r16 = lane & 15, q = lane >> 4;

  // stage A: 64 rows x 256 k, f32 -> f16
#pragma unroll
  for (int it = 0; it < 16; ++it) {
    int idx = tid + it * 256;
    int row = idx >> 6, c4 = (idx & 63) << 2;
    float4 v = *(const float4*)(x + (size_t)(rg * 64 + row) * 256 + c4);
    uint32_t* dp = (uint32_t*)&As[row][c4];
    dp[0] = pack2(v.x, v.y);
    dp[1] = pack2(v.z, v.w);
  }
  __syncthreads();

  const int a = cg >> 4;
  const int cbase = (cg & 15) * 64;
  const uint16_t* WTa = WT + (size_t)a * (1024 * 256);
  const float* bias = a == 0 ? bd : a == 1 ? bz : a == 2 ? br : bh;
  uint16_t* dst = a == 0 ? g_gamma : a == 1 ? g_xz : a == 2 ? g_xr : g_xh;
  const bool isg = (a == 0);

  const uint16_t* arow = &As[w * 16 + r16][q * 8];

#pragma unroll
  for (int nt = 0; nt < 4; ++nt) {
    int colg = cbase + nt * 16 + r16;
    const uint16_t* bcol = WTa + (size_t)colg * 256 + q * 8;
    f32x4 acc = {0.f, 0.f, 0.f, 0.f};
#pragma unroll
    for (int kc = 0; kc < 8; ++kc)
      acc = __builtin_amdgcn_mfma_f32_16x16x32_f16(
          *(const half8*)(arow + kc * 32), *(const half8*)(bcol + kc * 32),
          acc, 0, 0, 0);
    float bv = bias[colg];
#pragma unroll
    for (int j = 0; j < 4; ++j) {
      int n = rg * 64 + w * 16 + q * 4 + j;
      int b = n >> 9, t = n & 511;
      float p = acc[j] + bv;
      if (isg) p = __expf(-fmaxf(p, 0.f));
      dst[(((size_t)(t * 64 + b)) << 10) + colg] = f2h(p);
    }
  }
}

// ---- v13 scan (ack-ordered release exchange) — UNCHANGED ----------------

__global__ __launch_bounds__(256, 1) void scan_k(
    const uint16_t* __restrict__ UzT, const uint16_t* __restrict__ UrT,
    const uint16_t* __restrict__ UhT,
    const uint16_t* __restrict__ g_gamma, const uint16_t* __restrict__ g_xz,
    const uint16_t* __restrict__ g_xr, const uint16_t* __restrict__ g_xh,
    uint16_t* __restrict__ Hdat, uint16_t* __restrict__ RHdat,
    uint32_t* __restrict__ Htag, uint32_t* __restrict__ RHtag,
    float* __restrict__ out) {
  __shared__ __align__(16) uint16_t Hp[9][1032];   // rows 0-7, row 8 = zeros
  __shared__ __align__(16) uint16_t RHp[9][1032];
  __shared__ float red[4][4][256];
  __shared__ __align__(16) uint16_t pub16[8][32];  // own-block publish staging

  const int tid = threadIdx.x;
  const int g = blockIdx.x & 7;
  const int slot = blockIdx.x >> 3;
  const int c0 = slot * 32;
  const int lane = tid & 63, w = tid >> 6;
  const int r16 = lane & 15, q = lane >> 4;

  for (int i = tid; i < 1032; i += 256) { Hp[8][i] = 0; RHp[8][i] = 0; }

  // ---- one-time: B fragments (per wave: K in [w*256,+256))
  half8 Bz[2][8], Br[2][8], Bh[2][8];
#pragma unroll
  for (int ct = 0; ct < 2; ++ct) {
    const size_t colb = (size_t)(c0 + ct * 16 + r16) * 1024 + w * 256 + q * 8;
#pragma unroll
    for (int kc = 0; kc < 8; ++kc) {
      Bz[ct][kc] = *(const half8*)(UzT + colb + kc * 32);
      Br[ct][kc] = *(const half8*)(UrT + colb + kc * 32);
      Bh[ct][kc] = *(const half8*)(UhT + colb + kc * 32);
    }
  }
  __syncthreads();

  const uint16_t* aprow = Hp[r16 < 8 ? r16 : 8];
  const uint16_t* aprow2 = RHp[r16 < 8 ? r16 : 8];
  const int aoff = w * 256 + q * 8;

  // epilogue geometry: wave ct = w&1; rows erow..erow+3 (valid when lane<32)
  const int ect = w & 1;
  const int ecol = c0 + ect * 16 + r16;
  const int erow = q * 4;

  // tag slots: (group, producer slot) * 16 dwords (64B stride)
  uint32_t* mytagH = Htag + (g * 32 + slot) * 16;
  uint32_t* mytagR = RHtag + (g * 32 + slot) * 16;
  const uint32_t* tagH = Htag + (g * 32 + (tid & 31)) * 16;
  const uint32_t* tagR = RHtag + (g * 32 + (tid & 31)) * 16;

  auto poll_tags = [&](const uint32_t* tp, unsigned exp) {
    for (;;) {
      unsigned v = ld_cg_b32w(tp);
      __builtin_amdgcn_sched_barrier(0);
      if (__all((int)(v == exp))) break;
      __builtin_amdgcn_s_sleep(2);
    }
  };
  auto fill = [&](const uint16_t* dat, uint16_t (&panel)[9][1032]) {
    const uint32_t* src = (const uint32_t*)(dat +
        ((size_t)(g * 8 + (tid >> 5)) << 10) + (size_t)(tid & 31) * 32);
    u32x4 v0 = ld_cg_b128(src);
    u32x4 v1 = ld_cg_b128(src + 4);
    u32x4 v2 = ld_cg_b128(src + 8);
    u32x4 v3 = ld_cg_b128(src + 12);
    asm volatile("s_waitcnt vmcnt(0)" ::: "memory");
    __builtin_amdgcn_sched_barrier(0);
    uint16_t* dst = &panel[tid >> 5][(tid & 31) * 32];
    *(u32x4*)(dst + 0)  = v0;
    *(u32x4*)(dst + 8)  = v1;
    *(u32x4*)(dst + 16) = v2;
    *(u32x4*)(dst + 24) = v3;
  };
  auto publish = [&](uint16_t* dat, uint32_t* tagp, unsigned tagval) {
    if (tid < 32) {
      int r = tid >> 2;
      int cq = (tid & 3) * 8;
      uint32_t* dp = (uint32_t*)(dat + ((size_t)(g * 8 + r) << 10) + c0 + cq);
      st_cg_b128(dp, *(u32x4*)&pub16[r][cq]);
      asm volatile("s_waitcnt vmcnt(0)" ::: "memory");  // data acked at PoC
      if (tid == 0) st_cg_b32(tagp, tagval);            // then release tag
    }
  };

  for (int t = 0; t < NT; ++t) {
    // (a) prefetch gate streams (non-temporal; clamped rows for lane>=32)
    float xzv[4], xrv[4], xhv[4], gmv[4];
    {
      const int tg = (t + 1 < NT) ? t + 1 : t;
#pragma unroll
      for (int j = 0; j < 4; ++j) {
        int rr = erow + j; if (rr > 7) rr = 7;
        size_t base = (((size_t)(t * 64 + g * 8 + rr)) << 10) + ecol;
        if (w < 2) {
          xzv[j] = ldnt_h(&g_xz[base]);
          xhv[j] = ldnt_h(&g_xh[base]);
          gmv[j] = ldnt_h(&g_gamma[(((size_t)(tg * 64 + g * 8 + rr)) << 10) + ecol]);
          xrv[j] = 0.f;
        } else {
          xrv[j] = ldnt_h(&g_xr[base]);
          xzv[j] = xhv[j] = gmv[j] = 0.f;
        }
      }
    }

    // (b) wait for h_dec(t): tag spin then single panel read
    poll_tags(tagH, (unsigned)t);
    fill(Hdat, Hp);
    __syncthreads();  // (c) Hp ready; red free

    // (d) P1 MFMA: z and r partials over K-slice
    f32x4 az0 = {0.f,0.f,0.f,0.f}, az1 = {0.f,0.f,0.f,0.f};
    f32x4 ar0 = {0.f,0.f,0.f,0.f}, ar1 = {0.f,0.f,0.f,0.f};
#pragma unroll
    for (int kc = 0; kc < 8; ++kc) {
      half8 av = *(const half8*)(aprow + aoff + kc * 32);
      az0 = __builtin_amdgcn_mfma_f32_16x16x32_f16(av, Bz[0][kc], az0, 0, 0, 0);
      az1 = __builtin_amdgcn_mfma_f32_16x16x32_f16(av, Bz[1][kc], az1, 0, 0, 0);
      ar0 = __builtin_amdgcn_mfma_f32_16x16x32_f16(av, Br[0][kc], ar0, 0, 0, 0);
      ar1 = __builtin_amdgcn_mfma_f32_16x16x32_f16(av, Br[1][kc], ar1, 0, 0, 0);
    }
    *(f32x4*)&red[w][0][lane * 4] = az0;
    *(f32x4*)&red[w][1][lane * 4] = az1;
    *(f32x4*)&red[w][2][lane * 4] = ar0;
    *(f32x4*)&red[w][3][lane * 4] = ar1;
    __syncthreads();

    // (e) reduce tile w; waves 0,1 keep z,hd; waves 2,3 stage RH into pub16
    float zk[4] = {0.f,0.f,0.f,0.f}, hdk[4] = {0.f,0.f,0.f,0.f};
    {
      f32x4 s = *(const f32x4*)&red[0][w][lane * 4];
      s += *(const f32x4*)&red[1][w][lane * 4];
      s += *(const f32x4*)&red[2][w][lane * 4];
      s += *(const f32x4*)&red[3][w][lane * 4];
      if (lane < 32) {
        if (w < 2) {
#pragma unroll
          for (int j = 0; j < 4; ++j) {
            zk[j] = sigm(xzv[j] + s[j]);
            hdk[j] = h2f(Hp[erow + j][ecol]);
          }
        } else {
#pragma unroll
          for (int j = 0; j < 4; ++j) {
            float rg = sigm(xrv[j] + s[j]);
            float hd = h2f(Hp[erow + j][ecol]);
            pub16[erow + j][ect * 16 + r16] = f2h(rg * hd);
          }
        }
      }
    }
    __syncthreads();
    publish(RHdat, mytagR, (unsigned)(t + 1));

    // (f) wait for RH(t)
    poll_tags(tagR, (unsigned)(t + 1));
    fill(RHdat, RHp);
    __syncthreads();  // RHp ready; red consumed by all

    // (g) P2 MFMA: hprop partials
    f32x4 ah0 = {0.f,0.f,0.f,0.f}, ah1 = {0.f,0.f,0.f,0.f};
#pragma unroll
    for (int kc = 0; kc < 8; ++kc) {
      half8 av = *(const half8*)(aprow2 + aoff + kc * 32);
      ah0 = __builtin_amdgcn_mfma_f32_16x16x32_f16(av, Bh[0][kc], ah0, 0, 0, 0);
      ah1 = __builtin_amdgcn_mfma_f32_16x16x32_f16(av, Bh[1][kc], ah1, 0, 0, 0);
    }
    *(f32x4*)&red[w][0][lane * 4] = ah0;
    *(f32x4*)&red[w][1][lane * 4] = ah1;
    __syncthreads();

    // (h) reduce + combine + stage h_dec(t+1) into pub16; waves 0,1
    if (w < 2) {
      f32x4 s = *(const f32x4*)&red[0][w][lane * 4];
      s += *(const f32x4*)&red[1][w][lane * 4];
      s += *(const f32x4*)&red[2][w][lane * 4];
      s += *(const f32x4*)&red[3][w][lane * 4];
      if (lane < 32) {
#pragma unroll
        for (int j = 0; j < 4; ++j) {
          float hp = fast_tanh(xhv[j] + s[j]);
          float h = (1.f - zk[j]) * hdk[j] + zk[j] * hp;
          int b = g * 8 + erow + j;
          stnt_f(&out[((size_t)b * NT + t) * NH + ecol], h);
          pub16[erow + j][ect * 16 + r16] = f2h(gmv[j] * h);
        }
      }
    }
    __syncthreads();
    if (t + 1 < NT) publish(Hdat, mytagH, (unsigned)(t + 1));
  }
}

// ---- launch ------------------------------------------------------------

extern "C" void kernel_launch(void* const* d_in, const int* in_sizes, int n_in,
                              void* d_out, int out_size, void* d_ws, size_t ws_size,
                              hipStream_t stream) {
  const float* x  = (const float*)d_in[0];
  const float* Wd = (const float*)d_in[1];
  const float* bd = (const float*)d_in[2];
  const float* Wz = (const float*)d_in[3];
  const float* Wr = (const float*)d_in[4];
  const float* Wh = (const float*)d_in[5];
  const float* Uz = (const float*)d_in[6];
  const float* Ur = (const float*)d_in[7];
  const float* Uh = (const float*)d_in[8];
  const float* bz = (const float*)d_in[9];
  const float* br = (const float*)d_in[10];
  const float* bh = (const float*)d_in[11];
  float* out = (float*)d_out;

  char* ws = (char*)d_ws;
  size_t off = 0;
  auto take = [&](size_t bytes) -> char* {
    char* p = ws + off;
    off = (off + bytes + 255) & ~(size_t)255;
    return p;
  };
  uint16_t* WT  = (uint16_t*)take((size_t)4 * 1024 * 256 * 2);  // 2 MiB
  uint16_t* UzT = (uint16_t*)take((size_t)1024 * 1024 * 2);     // 2 MiB
  uint16_t* UrT = (uint16_t*)take((size_t)1024 * 1024 * 2);
  uint16_t* UhT = (uint16_t*)take((size_t)1024 * 1024 * 2);
  uint16_t* g_gamma = (uint16_t*)take((size_t)NT * NB * NH * 2); // 64 MiB
  uint16_t* g_xz   = (uint16_t*)take((size_t)NT * NB * NH * 2);
  uint16_t* g_xr   = (uint16_t*)take((size_t)NT * NB * NH * 2);
  uint16_t* g_xh   = (uint16_t*)take((size_t)NT * NB * NH * 2);
  uint16_t* Hdat   = (uint16_t*)take((size_t)NB * NH * 2);      // 128 KiB
  uint16_t* RHdat  = (uint16_t*)take((size_t)NB * NH * 2);      // 128 KiB
  uint32_t* Htag   = (uint32_t*)take((size_t)8 * 32 * 16 * 4);  // 16 KiB
  uint32_t* RHtag  = (uint32_t*)take((size_t)8 * 32 * 16 * 4);  // 16 KiB
  (void)ws_size; (void)in_sizes; (void)n_in; (void)out_size;

  (void)hipMemsetAsync(Hdat, 0, (size_t)NB * NH * 2, stream);      // h(0)=0
  (void)hipMemsetAsync(Htag, 0, (size_t)8 * 32 * 16 * 4, stream);  // tag0=ready
  (void)hipMemsetAsync(RHtag, 0, (size_t)8 * 32 * 16 * 4, stream); // tag0 (<1)

  // W^T (f16): [gate][1024 cols][256 k]
  transpose_f2h_g<<<64, 256, 0, stream>>>(Wd, WT + 0 * (1024 * 256), 256, 1024);
  transpose_f2h_g<<<64, 256, 0, stream>>>(Wz, WT + 1 * (1024 * 256), 256, 1024);
  transpose_f2h_g<<<64, 256, 0, stream>>>(Wr, WT + 2 * (1024 * 256), 256, 1024);
  transpose_f2h_g<<<64, 256, 0, stream>>>(Wh, WT + 3 * (1024 * 256), 256, 1024);
  // U^T (f16): [1024 cols][1024 k]
  transpose_f2h_g<<<256, 256, 0, stream>>>(Uz, UzT, 1024, 1024);
  transpose_f2h_g<<<256, 256, 0, stream>>>(Ur, UrT, 1024, 1024);
  transpose_f2h_g<<<256, 256, 0, stream>>>(Uh, UhT, 1024, 1024);

  proj_mfma_k<<<512 * 64, 256, 0, stream>>>(x, WT, bd, bz, br, bh,
                                            g_gamma, g_xz, g_xr, g_xh);

  scan_k<<<256, 256, 0, stream>>>(UzT, UrT, UhT, g_gamma, g_xz, g_xr, g_xh,
                                  Hdat, RHdat, Htag, RHtag, out);
}

// Round 16
// 3463.401 us; speedup vs baseline: 1.0743x; 1.0743x over previous
//
#include <hip/hip_runtime.h>
#include <cstdint>
#include <cstddef>

// GRU-D: B=64, T=512, D=256, H=1024.
// v15 = v14 with three LOCAL scan fixes (sync structure untouched):
//  1) fill(): lane-consecutive 16B chunks -> conflict-free LDS writes,
//     coalesced global reads (was 16-way bank conflict at 64B stride)
//  2) red[] -> SoA [producer][tile][comp][lane], b32 ops (was 8-way conflict)
//  3) out HBM stores moved to waves 2,3 AFTER the barrier, overlapping the
//     H publish -> tag release no longer waits on DRAM store completion.

#define NB 64
#define NT 512
#define ND 256
#define NH 1024

typedef _Float16 h2_t __attribute__((ext_vector_type(2)));
typedef _Float16 half8 __attribute__((ext_vector_type(8)));
typedef float f32x4 __attribute__((ext_vector_type(4)));
typedef uint32_t u32x4 __attribute__((ext_vector_type(4)));

__device__ __forceinline__ uint32_t pack2(float a, float b) {
  h2_t v; v[0] = (_Float16)a; v[1] = (_Float16)b;
  return __builtin_bit_cast(uint32_t, v);
}
__device__ __forceinline__ uint16_t f2h(float x) {
  _Float16 v = (_Float16)x; return __builtin_bit_cast(uint16_t, v);
}
__device__ __forceinline__ float h2f(uint16_t u) {
  return (float)__builtin_bit_cast(_Float16, u);
}
__device__ __forceinline__ float sigm(float x) {
  return 1.f / (1.f + __expf(-x));
}
__device__ __forceinline__ float fast_tanh(float x) {
  float e = __expf(2.f * x);
  return 1.f - 2.f / (e + 1.f);
}
__device__ __forceinline__ float ldnt_h(const uint16_t* p) {
  return h2f(__builtin_nontemporal_load(p));
}
__device__ __forceinline__ void stnt_f(float* p, float v) {
  __builtin_nontemporal_store(v, p);
}

// device-coherent (bypass L1/L2, served at MALL)
__device__ __forceinline__ u32x4 ld_cg_b128(const uint32_t* p) {
  u32x4 v;
  asm volatile("global_load_dwordx4 %0, %1, off sc0 sc1" : "=v"(v) : "v"(p) : "memory");
  return v;
}
__device__ __forceinline__ void st_cg_b128(uint32_t* p, u32x4 v) {
  asm volatile("global_store_dwordx4 %0, %1, off sc0 sc1" :: "v"(p), "v"(v) : "memory");
}
__device__ __forceinline__ void st_cg_b32(uint32_t* p, unsigned v) {
  asm volatile("global_store_dword %0, %1, off sc0 sc1" :: "v"(p), "v"(v) : "memory");
}
__device__ __forceinline__ unsigned ld_cg_b32w(const uint32_t* p) {
  unsigned v;
  asm volatile("global_load_dword %0, %1, off sc0 sc1\n\ts_waitcnt vmcnt(0)"
               : "=v"(v) : "v"(p) : "memory");
  return v;
}

// ---- generic transpose: src [R][C] f32 -> dst [C][R] f16, 64x64 tiles ---
__global__ __launch_bounds__(256) void transpose_f2h_g(
    const float* __restrict__ src, uint16_t* __restrict__ dst, int R, int C) {
  __shared__ uint16_t lt[64][68];
  int tpc = C >> 6;
  int tr = blockIdx.x / tpc, tc = blockIdx.x % tpc;
  int tid = threadIdx.x;
  int r0 = tid >> 6, cc = tid & 63;
#pragma unroll
  for (int it = 0; it < 16; ++it) {
    int r = it * 4 + r0;
    lt[cc][r] = f2h(src[(size_t)(tr * 64 + r) * C + tc * 64 + cc]);
  }
  __syncthreads();
#pragma unroll
  for (int it = 0; it < 16; ++it) {
    int c = it * 4 + r0;
    dst[(size_t)(tc * 64 + c) * R + tr * 64 + cc] = lt[c][cc];
  }
}

// ---- MFMA input projection (proven in v14) ------------------------------
__global__ __launch_bounds__(256) void proj_mfma_k(
    const float* __restrict__ x, const uint16_t* __restrict__ WT,
    const float* __restrict__ bd, const float* __restrict__ bz,
    const float* __restrict__ br, const float* __restrict__ bh,
    uint16_t* __restrict__ g_gamma, uint16_t* __restrict__ g_xz,
    uint16_t* __restrict__ g_xr, uint16_t* __restrict__ g_xh) {
  __shared__ __align__(16) uint16_t As[64][264];
  const int tid = threadIdx.x;
  const int rg = blockIdx.x >> 6;
  const int cg = blockIdx.x & 63;
  const int lane = tid & 63, w = tid >> 6;
  const int r16 = lane & 15, q = lane >> 4;

#pragma unroll
  for (int it = 0; it < 16; ++it) {
    int idx = tid + it * 256;
    int row = idx >> 6, c4 = (idx & 63) << 2;
    float4 v = *(const float4*)(x + (size_t)(rg * 64 + row) * 256 + c4);
    uint32_t* dp = (uint32_t*)&As[row][c4];
    dp[0] = pack2(v.x, v.y);
    dp[1] = pack2(v.z, v.w);
  }
  __syncthreads();

  const int a = cg >> 4;
  const int cbase = (cg & 15) * 64;
  const uint16_t* WTa = WT + (size_t)a * (1024 * 256);
  const float* bias = a == 0 ? bd : a == 1 ? bz : a == 2 ? br : bh;
  uint16_t* dst = a == 0 ? g_gamma : a == 1 ? g_xz : a == 2 ? g_xr : g_xh;
  const bool isg = (a == 0);

  const uint16_t* arow = &As[w * 16 + r16][q * 8];

#pragma unroll
  for (int nt = 0; nt < 4; ++nt) {
    int colg = cbase + nt * 16 + r16;
    const uint16_t* bcol = WTa + (size_t)colg * 256 + q * 8;
    f32x4 acc = {0.f, 0.f, 0.f, 0.f};
#pragma unroll
    for (int kc = 0; kc < 8; ++kc)
      acc = __builtin_amdgcn_mfma_f32_16x16x32_f16(
          *(const half8*)(arow + kc * 32), *(const half8*)(bcol + kc * 32),
          acc, 0, 0, 0);
    float bv = bias[colg];
#pragma unroll
    for (int j = 0; j < 4; ++j) {
      int n = rg * 64 + w * 16 + q * 4 + j;
      int b = n >> 9, t = n & 511;
      float p = acc[j] + bv;
      if (isg) p = __expf(-fmaxf(p, 0.f));
      dst[(((size_t)(t * 64 + b)) << 10) + colg] = f2h(p);
    }
  }
}

// ---- v15 scan -----------------------------------------------------------

__global__ __launch_bounds__(256, 1) void scan_k(
    const uint16_t* __restrict__ UzT, const uint16_t* __restrict__ UrT,
    const uint16_t* __restrict__ UhT,
    const uint16_t* __restrict__ g_gamma, const uint16_t* __restrict__ g_xz,
    const uint16_t* __restrict__ g_xr, const uint16_t* __restrict__ g_xh,
    uint16_t* __restrict__ Hdat, uint16_t* __restrict__ RHdat,
    uint32_t* __restrict__ Htag, uint32_t* __restrict__ RHtag,
    float* __restrict__ out) {
  __shared__ __align__(16) uint16_t Hp[9][1032];   // rows 0-7, row 8 = zeros
  __shared__ __align__(16) uint16_t RHp[9][1032];
  __shared__ float red[4][4][4][256];              // [prod][tile][comp][lane]
  __shared__ __align__(16) uint16_t pub16[8][32];  // publish staging
  __shared__ float outs[8][32];                    // out-store staging

  const int tid = threadIdx.x;
  const int g = blockIdx.x & 7;
  const int slot = blockIdx.x >> 3;
  const int c0 = slot * 32;
  const int lane = tid & 63, w = tid >> 6;
  const int r16 = lane & 15, q = lane >> 4;

  for (int i = tid; i < 1032; i += 256) { Hp[8][i] = 0; RHp[8][i] = 0; }

  // ---- one-time: B fragments (per wave: K in [w*256,+256))
  half8 Bz[2][8], Br[2][8], Bh[2][8];
#pragma unroll
  for (int ct = 0; ct < 2; ++ct) {
    const size_t colb = (size_t)(c0 + ct * 16 + r16) * 1024 + w * 256 + q * 8;
#pragma unroll
    for (int kc = 0; kc < 8; ++kc) {
      Bz[ct][kc] = *(const half8*)(UzT + colb + kc * 32);
      Br[ct][kc] = *(const half8*)(UrT + colb + kc * 32);
      Bh[ct][kc] = *(const half8*)(UhT + colb + kc * 32);
    }
  }
  __syncthreads();

  const uint16_t* aprow = Hp[r16 < 8 ? r16 : 8];
  const uint16_t* aprow2 = RHp[r16 < 8 ? r16 : 8];
  const int aoff = w * 256 + q * 8;

  const int ect = w & 1;
  const int ecol = c0 + ect * 16 + r16;
  const int erow = q * 4;

  uint32_t* mytagH = Htag + (g * 32 + slot) * 16;
  uint32_t* mytagR = RHtag + (g * 32 + slot) * 16;
  const uint32_t* tagH = Htag + (g * 32 + (tid & 31)) * 16;
  const uint32_t* tagR = RHtag + (g * 32 + (tid & 31)) * 16;

  auto poll_tags = [&](const uint32_t* tp, unsigned exp) {
    for (;;) {
      unsigned v = ld_cg_b32w(tp);
      __builtin_amdgcn_sched_barrier(0);
      if (__all((int)(v == exp))) break;
      __builtin_amdgcn_s_sleep(2);
    }
  };
  // lane-consecutive 16B chunks: conflict-free LDS writes, coalesced reads
  auto fill = [&](const uint16_t* dat, uint16_t (&panel)[9][1032]) {
    u32x4 v[4];
#pragma unroll
    for (int it = 0; it < 4; ++it) {
      int c = it * 256 + tid;  // 16B chunk id; row = c>>7, col = (c&127)*8 u16
      const uint32_t* src = (const uint32_t*)(dat +
          ((size_t)(g * 8 + (c >> 7)) << 10) + (size_t)(c & 127) * 8);
      v[it] = ld_cg_b128(src);
    }
    asm volatile("s_waitcnt vmcnt(0)" ::: "memory");
    __builtin_amdgcn_sched_barrier(0);
#pragma unroll
    for (int it = 0; it < 4; ++it) {
      int c = it * 256 + tid;
      *(u32x4*)&panel[c >> 7][(c & 127) * 8] = v[it];
    }
  };
  auto publish = [&](uint16_t* dat, uint32_t* tagp, unsigned tagval) {
    if (tid < 32) {
      int r = tid >> 2;
      int cq = (tid & 3) * 8;
      uint32_t* dp = (uint32_t*)(dat + ((size_t)(g * 8 + r) << 10) + c0 + cq);
      st_cg_b128(dp, *(u32x4*)&pub16[r][cq]);
      asm volatile("s_waitcnt vmcnt(0)" ::: "memory");  // data acked at PoC
      if (tid == 0) st_cg_b32(tagp, tagval);            // then release tag
    }
  };

  for (int t = 0; t < NT; ++t) {
    // (a) prefetch gate streams (non-temporal; clamped rows for lane>=32)
    float xzv[4], xrv[4], xhv[4], gmv[4];
    {
      const int tg = (t + 1 < NT) ? t + 1 : t;
#pragma unroll
      for (int j = 0; j < 4; ++j) {
        int rr = erow + j; if (rr > 7) rr = 7;
        size_t base = (((size_t)(t * 64 + g * 8 + rr)) << 10) + ecol;
        if (w < 2) {
          xzv[j] = ldnt_h(&g_xz[base]);
          xhv[j] = ldnt_h(&g_xh[base]);
          gmv[j] = ldnt_h(&g_gamma[(((size_t)(tg * 64 + g * 8 + rr)) << 10) + ecol]);
          xrv[j] = 0.f;
        } else {
          xrv[j] = ldnt_h(&g_xr[base]);
          xzv[j] = xhv[j] = gmv[j] = 0.f;
        }
      }
    }

    // (b) wait for h_dec(t): tag spin then single panel read
    poll_tags(tagH, (unsigned)t);
    fill(Hdat, Hp);
    __syncthreads();  // (c) Hp ready; red free

    // (d) P1 MFMA: z and r partials over K-slice
    f32x4 az0 = {0.f,0.f,0.f,0.f}, az1 = {0.f,0.f,0.f,0.f};
    f32x4 ar0 = {0.f,0.f,0.f,0.f}, ar1 = {0.f,0.f,0.f,0.f};
#pragma unroll
    for (int kc = 0; kc < 8; ++kc) {
      half8 av = *(const half8*)(aprow + aoff + kc * 32);
      az0 = __builtin_amdgcn_mfma_f32_16x16x32_f16(av, Bz[0][kc], az0, 0, 0, 0);
      az1 = __builtin_amdgcn_mfma_f32_16x16x32_f16(av, Bz[1][kc], az1, 0, 0, 0);
      ar0 = __builtin_amdgcn_mfma_f32_16x16x32_f16(av, Br[0][kc], ar0, 0, 0, 0);
      ar1 = __builtin_amdgcn_mfma_f32_16x16x32_f16(av, Br[1][kc], ar1, 0, 0, 0);
    }
#pragma unroll
    for (int k = 0; k < 4; ++k) {
      red[w][0][k][lane] = az0[k];
      red[w][1][k][lane] = az1[k];
      red[w][2][k][lane] = ar0[k];
      red[w][3][k][lane] = ar1[k];
    }
    __syncthreads();

    // (e) reduce tile w; waves 0,1 keep z,hd; waves 2,3 stage RH into pub16
    float zk[4] = {0.f,0.f,0.f,0.f}, hdk[4] = {0.f,0.f,0.f,0.f};
    {
      f32x4 s;
#pragma unroll
      for (int k = 0; k < 4; ++k)
        s[k] = red[0][w][k][lane] + red[1][w][k][lane] +
               red[2][w][k][lane] + red[3][w][k][lane];
      if (lane < 32) {
        if (w < 2) {
#pragma unroll
          for (int j = 0; j < 4; ++j) {
            zk[j] = sigm(xzv[j] + s[j]);
            hdk[j] = h2f(Hp[erow + j][ecol]);
          }
        } else {
#pragma unroll
          for (int j = 0; j < 4; ++j) {
            float rg = sigm(xrv[j] + s[j]);
            float hd = h2f(Hp[erow + j][ecol]);
            pub16[erow + j][ect * 16 + r16] = f2h(rg * hd);
          }
        }
      }
    }
    __syncthreads();
    publish(RHdat, mytagR, (unsigned)(t + 1));

    // (f) wait for RH(t)
    poll_tags(tagR, (unsigned)(t + 1));
    fill(RHdat, RHp);
    __syncthreads();  // RHp ready; red consumed by all

    // (g) P2 MFMA: hprop partials
    f32x4 ah0 = {0.f,0.f,0.f,0.f}, ah1 = {0.f,0.f,0.f,0.f};
#pragma unroll
    for (int kc = 0; kc < 8; ++kc) {
      half8 av = *(const half8*)(aprow2 + aoff + kc * 32);
      ah0 = __builtin_amdgcn_mfma_f32_16x16x32_f16(av, Bh[0][kc], ah0, 0, 0, 0);
      ah1 = __builtin_amdgcn_mfma_f32_16x16x32_f16(av, Bh[1][kc], ah1, 0, 0, 0);
    }
#pragma unroll
    for (int k = 0; k < 4; ++k) {
      red[w][0][k][lane] = ah0[k];
      red[w][1][k][lane] = ah1[k];
    }
    __syncthreads();

    // (h) reduce + combine; waves 0,1 stage h' into pub16 AND h into outs
    if (w < 2) {
      f32x4 s;
#pragma unroll
      for (int k = 0; k < 4; ++k)
        s[k] = red[0][w][k][lane] + red[1][w][k][lane] +
               red[2][w][k][lane] + red[3][w][k][lane];
      if (lane < 32) {
#pragma unroll
        for (int j = 0; j < 4; ++j) {
          float hp = fast_tanh(xhv[j] + s[j]);
          float h = (1.f - zk[j]) * hdk[j] + zk[j] * hp;
          outs[erow + j][ect * 16 + r16] = h;
          pub16[erow + j][ect * 16 + r16] = f2h(gmv[j] * h);
        }
      }
    }
    __syncthreads();
    // publish H (waves 0; tag not blocked by DRAM) || out stores (waves 2,3)
    if (t + 1 < NT) publish(Hdat, mytagH, (unsigned)(t + 1));
    if (w >= 2) {
      int idx = tid - 128;  // 0..127, 2 values each
#pragma unroll
      for (int k = 0; k < 2; ++k) {
        int ii = idx * 2 + k;
        int r = ii >> 5, cc = ii & 31;
        stnt_f(&out[((size_t)(g * 8 + r) * NT + t) * NH + c0 + cc], outs[r][cc]);
      }
    }
  }
}

// ---- launch ------------------------------------------------------------

extern "C" void kernel_launch(void* const* d_in, const int* in_sizes, int n_in,
                              void* d_out, int out_size, void* d_ws, size_t ws_size,
                              hipStream_t stream) {
  const float* x  = (const float*)d_in[0];
  const float* Wd = (const float*)d_in[1];
  const float* bd = (const float*)d_in[2];
  const float* Wz = (const float*)d_in[3];
  const float* Wr = (const float*)d_in[4];
  const float* Wh = (const float*)d_in[5];
  const float* Uz = (const float*)d_in[6];
  const float* Ur = (const float*)d_in[7];
  const float* Uh = (const float*)d_in[8];
  const float* bz = (const float*)d_in[9];
  const float* br = (const float*)d_in[10];
  const float* bh = (const float*)d_in[11];
  float* out = (float*)d_out;

  char* ws = (char*)d_ws;
  size_t off = 0;
  auto take = [&](size_t bytes) -> char* {
    char* p = ws + off;
    off = (off + bytes + 255) & ~(size_t)255;
    return p;
  };
  uint16_t* WT  = (uint16_t*)take((size_t)4 * 1024 * 256 * 2);  // 2 MiB
  uint16_t* UzT = (uint16_t*)take((size_t)1024 * 1024 * 2);     // 2 MiB
  uint16_t* UrT = (uint16_t*)take((size_t)1024 * 1024 * 2);
  uint16_t* UhT = (uint16_t*)take((size_t)1024 * 1024 * 2);
  uint16_t* g_gamma = (uint16_t*)take((size_t)NT * NB * NH * 2); // 64 MiB
  uint16_t* g_xz   = (uint16_t*)take((size_t)NT * NB * NH * 2);
  uint16_t* g_xr   = (uint16_t*)take((size_t)NT * NB * NH * 2);
  uint16_t* g_xh   = (uint16_t*)take((size_t)NT * NB * NH * 2);
  uint16_t* Hdat   = (uint16_t*)take((size_t)NB * NH * 2);      // 128 KiB
  uint16_t* RHdat  = (uint16_t*)take((size_t)NB * NH * 2);      // 128 KiB
  uint32_t* Htag   = (uint32_t*)take((size_t)8 * 32 * 16 * 4);  // 16 KiB
  uint32_t* RHtag  = (uint32_t*)take((size_t)8 * 32 * 16 * 4);  // 16 KiB
  (void)ws_size; (void)in_sizes; (void)n_in; (void)out_size;

  (void)hipMemsetAsync(Hdat, 0, (size_t)NB * NH * 2, stream);      // h(0)=0
  (void)hipMemsetAsync(Htag, 0, (size_t)8 * 32 * 16 * 4, stream);  // tag0=ready
  (void)hipMemsetAsync(RHtag, 0, (size_t)8 * 32 * 16 * 4, stream); // tag0 (<1)

  transpose_f2h_g<<<64, 256, 0, stream>>>(Wd, WT + 0 * (1024 * 256), 256, 1024);
  transpose_f2h_g<<<64, 256, 0, stream>>>(Wz, WT + 1 * (1024 * 256), 256, 1024);
  transpose_f2h_g<<<64, 256, 0, stream>>>(Wr, WT + 2 * (1024 * 256), 256, 1024);
  transpose_f2h_g<<<64, 256, 0, stream>>>(Wh, WT + 3 * (1024 * 256), 256, 1024);
  transpose_f2h_g<<<256, 256, 0, stream>>>(Uz, UzT, 1024, 1024);
  transpose_f2h_g<<<256, 256, 0, stream>>>(Ur, UrT, 1024, 1024);
  transpose_f2h_g<<<256, 256, 0, stream>>>(Uh, UhT, 1024, 1024);

  proj_mfma_k<<<512 * 64, 256, 0, stream>>>(x, WT, bd, bz, br, bh,
                                            g_gamma, g_xz, g_xr, g_xh);

  scan_k<<<256, 256, 0, stream>>>(UzT, UrT, UhT, g_gamma, g_xz, g_xr, g_xh,
                                  Hdat, RHdat, Htag, RHtag, out);
}